// Round 10
// baseline (422.881 us; speedup 1.0000x reference)
//
#include <hip/hip_runtime.h>
#include <hip/hip_bf16.h>
#include <math.h>

// MHSA: B=8, DIM=512, H=W=32, HEAD=8, DH=64, N=1024
// Round 8 (3rd resubmit; R8/R9 benches were broker timeouts): flash_pv latency
// fixes — occupancy 2->4 blocks/CU, double-buffered V staging with ONE barrier
// per tile (stage nt+1 overlaps compute nt). Static A/B buffer names.
#define BB   8
#define DIMC 512
#define HEAD 8
#define DH   64
#define NN   1024
#define HW   32

typedef __attribute__((ext_vector_type(8))) __bf16 bf16x8;
typedef __attribute__((ext_vector_type(4))) float  f32x4;
typedef __attribute__((ext_vector_type(4))) short  short4v;

#define MFMA16(a, b, c) __builtin_amdgcn_mfma_f32_16x16x32_bf16((a), (b), (c), 0, 0, 0)

__device__ __forceinline__ f32x4 mfma_pv(short4v a, short4v b, f32x4 c) {
#if __has_builtin(__builtin_amdgcn_mfma_f32_16x16x16bf16_1k)
    return __builtin_amdgcn_mfma_f32_16x16x16bf16_1k(a, b, c, 0, 0, 0);
#else
    asm volatile("v_mfma_f32_16x16x16_bf16 %0, %1, %2, %0"
                 : "+v"(c) : "v"(a), "v"(b));
    return c;
#endif
}

// swizzled element offset in a [rows][64 bf16] LDS tile (rows = 128 B).
__device__ __forceinline__ int SW(int row, int col) {
    return (row << 6) + (col ^ ((row & 7) << 3));
}

__device__ __forceinline__ unsigned short bfh(float v) {   // fp32 -> bf16 (RNE)
    unsigned int u = __float_as_uint(v);
    return (unsigned short)((u + 0x7fffu + ((u >> 16) & 1u)) >> 16);
}
__device__ __forceinline__ float bf2f(unsigned short h) {
    return __uint_as_float(((unsigned int)h) << 16);
}

// ---------------- prep: x transpose + split ----------------
__global__ __launch_bounds__(256)
void prep_x(const float* __restrict__ x,
            unsigned short* __restrict__ XTh, unsigned short* __restrict__ XTl)
{
    const int tid = threadIdx.x;
    const int nt = blockIdx.x;     // 16
    const int ct = blockIdx.y;     // 8
    const int b  = blockIdx.z;     // 8
    const int c0 = ct << 6, n0 = nt << 6;

    __shared__ float XsT[64][68];  // [n][c]

    #pragma unroll
    for (int p = 0; p < 4; ++p) {
        int idx = tid + (p << 8);
        int cr = idx >> 4;
        int nc4 = (idx & 15) << 2;
        float4 v = *(const float4*)&x[((size_t)b * DIMC + c0 + cr) * NN + n0 + nc4];
        XsT[nc4 + 0][cr] = v.x;
        XsT[nc4 + 1][cr] = v.y;
        XsT[nc4 + 2][cr] = v.z;
        XsT[nc4 + 3][cr] = v.w;
    }
    __syncthreads();
    #pragma unroll
    for (int p = 0; p < 4; ++p) {
        int idx = tid + (p << 8);
        int n = idx >> 4;
        int c4 = (idx & 15) << 2;
        float4 v = *(const float4*)&XsT[n][c4];
        float vv[4] = {v.x, v.y, v.z, v.w};
        union { unsigned short u[4]; uint2 w; } ph, pl;
        #pragma unroll
        for (int j = 0; j < 4; ++j) {
            unsigned short hh = bfh(vv[j]);
            ph.u[j] = hh;
            pl.u[j] = bfh(vv[j] - bf2f(hh));
        }
        size_t off = ((size_t)(b * NN + n0 + n)) * DIMC + c0 + c4;
        *(uint2*)&XTh[off] = ph.w;
        *(uint2*)&XTl[off] = pl.w;
    }
}

// ---------------- prep: weight split ----------------
__global__ __launch_bounds__(256)
void prep_w(const float* __restrict__ wq, const float* __restrict__ wk,
            const float* __restrict__ wv,
            unsigned short* __restrict__ Wh, unsigned short* __restrict__ Wl)
{
    const int z = blockIdx.y;
    const float* src = (z == 0) ? wq : (z == 1) ? wk : wv;
    const size_t zb = (size_t)z * DIMC * DIMC;
    #pragma unroll
    for (int p = 0; p < 4; ++p) {
        size_t i = (size_t)blockIdx.x * 4096 + (p << 10) + (threadIdx.x << 2);
        float4 v = *(const float4*)&src[i];
        float vv[4] = {v.x, v.y, v.z, v.w};
        union { unsigned short u[4]; uint2 w; } ph, pl;
        #pragma unroll
        for (int j = 0; j < 4; ++j) {
            unsigned short hh = bfh(vv[j]);
            ph.u[j] = hh;
            pl.u[j] = bfh(vv[j] - bf2f(hh));
        }
        *(uint2*)&Wh[zb + i] = ph.w;
        *(uint2*)&Wl[zb + i] = pl.w;
    }
}

// ---------------- qkv GEMM (MFMA) ----------------
__global__ __launch_bounds__(256)
void qkv_gemm(const unsigned short* __restrict__ XTh, const unsigned short* __restrict__ XTl,
              const unsigned short* __restrict__ Wh, const unsigned short* __restrict__ Wl,
              const float* __restrict__ wq_b, const float* __restrict__ wk_b,
              const float* __restrict__ wv_b,
              const float* __restrict__ r_h, const float* __restrict__ r_w,
              unsigned short* __restrict__ Qh, unsigned short* __restrict__ Ql,
              unsigned short* __restrict__ Kh, unsigned short* __restrict__ Kl,
              unsigned short* __restrict__ Vh, unsigned short* __restrict__ Vl)
{
    const int tid = threadIdx.x;
    const int z = blockIdx.z, hd = blockIdx.y;
    const int gn = blockIdx.x << 7;
    const int b = gn >> 10, posb = gn & 1023;
    const int oB = hd << 6;
    const int lane = tid & 63, w = tid >> 6;

    __shared__ __align__(16) unsigned short sm[24576];  // 48 KB
    unsigned short* Ah = sm;
    unsigned short* Al = sm + 4096;
    unsigned short* Bh = sm + 8192;
    unsigned short* Bl = sm + 16384;

    const float* bias = (z == 0) ? wq_b : (z == 1) ? wk_b : wv_b;
    const unsigned short* wsh = Wh + (size_t)z * DIMC * DIMC + (size_t)oB * DIMC;
    const unsigned short* wsl = Wl + (size_t)z * DIMC * DIMC + (size_t)oB * DIMC;
    const unsigned short* xth = XTh + ((size_t)(b * NN + posb)) * DIMC;
    const unsigned short* xtl = XTl + ((size_t)(b * NN + posb)) * DIMC;

    f32x4 acc[8];
    #pragma unroll
    for (int t = 0; t < 8; ++t) acc[t] = (f32x4){0.f, 0.f, 0.f, 0.f};

    for (int ks = 0; ks < 8; ++ks) {
        const int c0 = ks << 6;
        #pragma unroll
        for (int p = 0; p < 2; ++p) {
            int idx = (p << 8) + tid;
            int row = idx >> 3, col8 = (idx & 7) << 3;
            size_t g = (size_t)row * DIMC + c0 + col8;
            *(float4*)&Ah[SW(row, col8)] = *(const float4*)&wsh[g];
            *(float4*)&Al[SW(row, col8)] = *(const float4*)&wsl[g];
        }
        #pragma unroll
        for (int p = 0; p < 4; ++p) {
            int idx = (p << 8) + tid;
            int row = idx >> 3, col8 = (idx & 7) << 3;
            size_t g = (size_t)row * DIMC + c0 + col8;
            *(float4*)&Bh[SW(row, col8)] = *(const float4*)&xth[g];
            *(float4*)&Bl[SW(row, col8)] = *(const float4*)&xtl[g];
        }
        __syncthreads();

        const int ar = (w << 4) + (lane & 15);
        const int kc = (lane >> 4) << 3;
        bf16x8 ah[2], al[2];
        ah[0] = *(const bf16x8*)&Ah[SW(ar, kc)];
        ah[1] = *(const bf16x8*)&Ah[SW(ar, 32 + kc)];
        al[0] = *(const bf16x8*)&Al[SW(ar, kc)];
        al[1] = *(const bf16x8*)&Al[SW(ar, 32 + kc)];
        #pragma unroll
        for (int t = 0; t < 8; ++t) {
            int br = (t << 4) + (lane & 15);
            #pragma unroll
            for (int s = 0; s < 2; ++s) {
                bf16x8 xh = *(const bf16x8*)&Bh[SW(br, s * 32 + kc)];
                bf16x8 xl = *(const bf16x8*)&Bl[SW(br, s * 32 + kc)];
                acc[t] = MFMA16(ah[s], xh, acc[t]);
                acc[t] = MFMA16(ah[s], xl, acc[t]);
                acc[t] = MFMA16(al[s], xh, acc[t]);
            }
        }
        __syncthreads();
    }

    float* F = (float*)sm;    // [64][132]
    #pragma unroll
    for (int t = 0; t < 8; ++t) {
        int n = (t << 4) + (lane & 15);
        #pragma unroll
        for (int r = 0; r < 4; ++r) {
            int o = (w << 4) + ((lane >> 4) << 2) + r;
            F[o * 132 + n] = acc[t][r];
        }
    }
    __syncthreads();

    const size_t bh = (size_t)(b * HEAD + hd);
    if (z != 2) {
        unsigned short* Dh = (z == 0) ? Qh : Kh;
        unsigned short* Dl = (z == 0) ? Ql : Kl;
        #pragma unroll
        for (int p = 0; p < 8; ++p) {
            int idx = (p << 8) + tid;
            int n = idx >> 4, d0 = (idx & 15) << 2;
            union { unsigned short u[4]; uint2 v; } ph, pl;
            #pragma unroll
            for (int i = 0; i < 4; ++i) {
                int d = d0 + i;
                float val = F[d * 132 + n] + bias[oB + d];
                if (z == 1) {
                    int m = posb + n;
                    val += r_h[(size_t)(oB + d) * HW + (m & 31)]
                         + r_w[(size_t)(oB + d) * HW + (m >> 5)];
                }
                unsigned short hh = bfh(val);
                ph.u[i] = hh;
                pl.u[i] = bfh(val - bf2f(hh));
            }
            size_t off = (((size_t)bh * NN + posb + n) << 6) + d0;
            *(uint2*)&Dh[off] = ph.v;
            *(uint2*)&Dl[off] = pl.v;
        }
    } else {
        #pragma unroll
        for (int p = 0; p < 8; ++p) {
            int idx = (p << 8) + tid;
            int d = idx >> 5, n0 = (idx & 31) << 2;
            float4 v = *(const float4*)&F[d * 132 + n0];
            float vv[4] = {v.x, v.y, v.z, v.w};
            float bia = bias[oB + d];
            union { unsigned short u[4]; uint2 w2; } ph, pl;
            #pragma unroll
            for (int j = 0; j < 4; ++j) {
                float val = vv[j] + bia;
                unsigned short hh = bfh(val);
                ph.u[j] = hh;
                pl.u[j] = bfh(val - bf2f(hh));
            }
            size_t off = (((size_t)bh << 6) + d) * NN + posb + n0;
            *(uint2*)&Vh[off] = ph.w2;
            *(uint2*)&Vl[off] = pl.w2;
        }
    }
}

// ---------------- flash_pv helpers ----------------
#define STAGE_V(nB, Dh, Dl)                                                        \
    {                                                                              \
        _Pragma("unroll")                                                          \
        for (int p = 0; p < 2; ++p) {                                              \
            int idx = (p << 8) + tid;                                              \
            int row = idx >> 3, c8 = (idx & 7) << 3;                               \
            *(float4*)&(Dh)[SW(row, c8)] =                                         \
                *(const float4*)&vh[(size_t)row * NN + (nB) + c8];                 \
            *(float4*)&(Dl)[SW(row, c8)] =                                         \
                *(const float4*)&vl[(size_t)row * NN + (nB) + c8];                 \
        }                                                                          \
    }

__device__ __forceinline__ void tile_step(
    int nB, int w, int r0, int c0, int tid,
    const unsigned short* __restrict__ qh, const unsigned short* __restrict__ ql,
    const bf16x8 (&kfh)[4][2], const bf16x8 (&kfl)[4][2],
    const unsigned short* Vsh, const unsigned short* Vsl,
    float& m_w, float& s_r, f32x4 (&facc)[4][4])
{
    // Q fragments for this wave's 16 n-rows: global -> reg
    const int qrow = nB + (w << 4) + r0;
    const size_t qb = ((size_t)qrow << 6) + c0;
    bf16x8 ah0 = *(const bf16x8*)&qh[qb];
    bf16x8 ah1 = *(const bf16x8*)&qh[qb + 32];
    bf16x8 al0 = *(const bf16x8*)&ql[qb];
    bf16x8 al1 = *(const bf16x8*)&ql[qb + 32];

    // logits S (3-term split)
    f32x4 sacc[4];
    #pragma unroll
    for (int t = 0; t < 4; ++t) sacc[t] = (f32x4){0.f, 0.f, 0.f, 0.f};
    #pragma unroll
    for (int t = 0; t < 4; ++t) {
        sacc[t] = MFMA16(ah0, kfh[t][0], sacc[t]);
        sacc[t] = MFMA16(ah0, kfl[t][0], sacc[t]);
        sacc[t] = MFMA16(al0, kfh[t][0], sacc[t]);
    }
    #pragma unroll
    for (int t = 0; t < 4; ++t) {
        sacc[t] = MFMA16(ah1, kfh[t][1], sacc[t]);
        sacc[t] = MFMA16(ah1, kfl[t][1], sacc[t]);
        sacc[t] = MFMA16(al1, kfh[t][1], sacc[t]);
    }

    // online max: lane max -> wave max (shfl butterfly), rescale on increase
    float tmax = -1e30f;
    #pragma unroll
    for (int t = 0; t < 4; ++t)
        #pragma unroll
        for (int r = 0; r < 4; ++r) tmax = fmaxf(tmax, sacc[t][r]);
    #pragma unroll
    for (int off = 1; off < 64; off <<= 1)
        tmax = fmaxf(tmax, __shfl_xor(tmax, off, 64));
    if (tmax > m_w) {                      // wave-uniform branch
        float sc = __expf(m_w - tmax);     // exp(-inf)=0 on first tile
        s_r *= sc;
        #pragma unroll
        for (int u = 0; u < 4; ++u)
            #pragma unroll
            for (int t = 0; t < 4; ++t) facc[u][t] *= sc;
        m_w = tmax;
    }

    // P = exp(S - m_w) in-register, split hi/lo; accumulate s
    short4v pah[4], pal[4];
    #pragma unroll
    for (int t = 0; t < 4; ++t) {
        union { unsigned short u[4]; short4v v; } Ph, Pl;
        #pragma unroll
        for (int r = 0; r < 4; ++r) {
            float a = __expf(sacc[t][r] - m_w);
            s_r += a;
            unsigned short hh = bfh(a);
            Ph.u[r] = hh;
            Pl.u[r] = bfh(a - bf2f(hh));
        }
        pah[t] = Ph.v;
        pal[t] = Pl.v;
    }

    // PV: F^T[d][m] partial over this wave's 16 n (K=16 MFMA)
    const int lane_hi = (tid & 63) >> 4;
    const int vcol = (w << 4) + (lane_hi << 2);
    #pragma unroll
    for (int u = 0; u < 4; ++u) {
        int vrow = (u << 4) + r0;
        short4v vah = *(const short4v*)&Vsh[SW(vrow, vcol)];
        short4v vbl = *(const short4v*)&Vsl[SW(vrow, vcol)];
        #pragma unroll
        for (int t = 0; t < 4; ++t) {
            facc[u][t] = mfma_pv(vah, pah[t], facc[u][t]);
            facc[u][t] = mfma_pv(vbl, pah[t], facc[u][t]);
            facc[u][t] = mfma_pv(vah, pal[t], facc[u][t]);
        }
    }
}

// ---------------- flash_pv: single-pass, double-buffered V, 1 barrier/tile ----
__global__ __launch_bounds__(256, 4)
void flash_pv(const unsigned short* __restrict__ Qh, const unsigned short* __restrict__ Ql,
              const unsigned short* __restrict__ Kh, const unsigned short* __restrict__ Kl,
              const unsigned short* __restrict__ Vh, const unsigned short* __restrict__ Vl,
              float* __restrict__ pooled, float* __restrict__ pstats)
{
    const int tid = threadIdx.x;
    const int mt = blockIdx.x, hd = blockIdx.y, b = blockIdx.z;
    const int bh = b * HEAD + hd;
    const int lane = tid & 63, w = tid >> 6;
    const int r0 = lane & 15, c0 = (lane >> 4) << 3;

    // LDS: 2 x (Vsh+Vsl) double buffer (32 KB) in loop; F0/F1 fp32 (33.3 KB) epilogue
    __shared__ __align__(16) unsigned char smraw[2 * 64 * 65 * 4];
    unsigned short* VshA = (unsigned short*)smraw;
    unsigned short* VslA = VshA + 4096;
    unsigned short* VshB = VshA + 8192;
    unsigned short* VslB = VshA + 12288;
    float* F0 = (float*)smraw;
    float* F1 = F0 + 64 * 65;
    __shared__ float bm[4], bs[4];

    // K fragments: global -> reg, once
    const unsigned short* kh = Kh + (((size_t)bh * NN + (mt << 6)) << 6);
    const unsigned short* kl = Kl + (((size_t)bh * NN + (mt << 6)) << 6);
    bf16x8 kfh[4][2], kfl[4][2];
    #pragma unroll
    for (int t = 0; t < 4; ++t)
        #pragma unroll
        for (int s = 0; s < 2; ++s) {
            int off = (((t << 4) + r0) << 6) + (s << 5) + c0;
            kfh[t][s] = *(const bf16x8*)&kh[off];
            kfl[t][s] = *(const bf16x8*)&kl[off];
        }

    const unsigned short* qh = Qh + (((size_t)bh * NN) << 6);
    const unsigned short* ql = Ql + (((size_t)bh * NN) << 6);
    const unsigned short* vh = Vh + (((size_t)bh << 6) * NN);
    const unsigned short* vl = Vl + (((size_t)bh << 6) * NN);

    float m_w = -1e30f;   // wave-uniform running max
    float s_r = 0.f;      // per-lane partial sumexp (normalizer m_w)

    f32x4 facc[4][4];     // [d-tile u][m-tile t], unnormalized F^T partial
    #pragma unroll
    for (int u = 0; u < 4; ++u)
        #pragma unroll
        for (int t = 0; t < 4; ++t) facc[u][t] = (f32x4){0.f, 0.f, 0.f, 0.f};

    // prologue: stage tile 0 into A
    STAGE_V(0, VshA, VslA);
    __syncthreads();

    // 2x-unrolled main loop: static buffer names, 1 barrier per tile.
    // stage(nt+1) issues BEFORE compute(nt) -> V latency hides under QK+softmax.
    for (int ntp = 0; ntp < 8; ++ntp) {
        const int nt0 = ntp << 1;
        STAGE_V((nt0 + 1) << 6, VshB, VslB);
        tile_step(nt0 << 6, w, r0, c0, tid, qh, ql, kfh, kfl, VshA, VslA,
                  m_w, s_r, facc);
        __syncthreads();   // B staged; A reads done
        if (ntp < 7) STAGE_V((nt0 + 2) << 6, VshA, VslA);
        tile_step((nt0 + 1) << 6, w, r0, c0, tid, qh, ql, kfh, kfl, VshB, VslB,
                  m_w, s_r, facc);
        __syncthreads();   // A staged; B reads done
    }

    // ---- per-wave s reduce, block (m_B, s_B) combine ----
    #pragma unroll
    for (int off = 1; off < 64; off <<= 1) s_r += __shfl_xor(s_r, off, 64);
    if (lane == 0) { bm[w] = m_w; bs[w] = s_r; }
    __syncthreads();
    const float m_B = fmaxf(fmaxf(bm[0], bm[1]), fmaxf(bm[2], bm[3]));
    const float s_B = bs[0] * __expf(bm[0] - m_B) + bs[1] * __expf(bm[1] - m_B)
                    + bs[2] * __expf(bm[2] - m_B) + bs[3] * __expf(bm[3] - m_B);
    const float fsc = __expf(m_w - m_B);
    #pragma unroll
    for (int u = 0; u < 4; ++u)
        #pragma unroll
        for (int t = 0; t < 4; ++t) facc[u][t] *= fsc;
    if (tid == 0) {
        pstats[((b << 7) + (hd << 4) + mt) * 2 + 0] = m_B;
        pstats[((b << 7) + (hd << 4) + mt) * 2 + 1] = s_B;
    }

    // ---- cross-wave reduction of partial F^T, then 2x2 avg-pool (unnormalized) ----
    const int fr = (lane >> 4) << 2;
    if (w < 2) {
        float* Fw = (w == 0) ? F0 : F1;
        #pragma unroll
        for (int u = 0; u < 4; ++u)
            #pragma unroll
            for (int t = 0; t < 4; ++t)
                #pragma unroll
                for (int r = 0; r < 4; ++r)
                    Fw[((u << 4) + fr + r) * 65 + (t << 4) + r0] = facc[u][t][r];
    }
    __syncthreads();
    if (w >= 2) {
        float* Fw = (w == 2) ? F0 : F1;
        #pragma unroll
        for (int u = 0; u < 4; ++u)
            #pragma unroll
            for (int t = 0; t < 4; ++t)
                #pragma unroll
                for (int r = 0; r < 4; ++r)
                    Fw[((u << 4) + fr + r) * 65 + (t << 4) + r0] += facc[u][t][r];
    }
    __syncthreads();
    #pragma unroll
    for (int q = 0; q < 4; ++q) {
        int idx = (tid << 2) + q;
        int d = idx >> 4, wo = idx & 15;
        int m0 = wo << 1;
        float v = 0.25f * ((F0[d * 65 + m0]      + F1[d * 65 + m0]) +
                           (F0[d * 65 + m0 + 1]  + F1[d * 65 + m0 + 1]) +
                           (F0[d * 65 + 32 + m0] + F1[d * 65 + 32 + m0]) +
                           (F0[d * 65 + 33 + m0] + F1[d * 65 + 33 + m0]));
        pooled[(((size_t)(b * DIMC + (hd << 6) + d) << 4) + mt) * 16 + wo] = v;
    }
}

__global__ __launch_bounds__(128)
void combine_kernel(const float* __restrict__ pstats, float* __restrict__ gstats)
{
    const int b = blockIdx.x, tid = threadIdx.x;
    __shared__ float rm[128], rs[128];
    rm[tid] = pstats[((b << 7) + tid) * 2 + 0];
    rs[tid] = pstats[((b << 7) + tid) * 2 + 1];
    __syncthreads();
    for (int off = 64; off > 0; off >>= 1) {
        if (tid < off) {
            float m2 = rm[tid + off], s2 = rs[tid + off];
            float M = fmaxf(rm[tid], m2);
            rs[tid] = rs[tid] * __expf(rm[tid] - M) + s2 * __expf(m2 - M);
            rm[tid] = M;
        }
        __syncthreads();
    }
    if (tid == 0) { gstats[b * 2] = rm[0]; gstats[b * 2 + 1] = rs[0]; }
}

// ---------------- finalize: scale pooled by exp(m_B-gmax)/gsum ----------------
__global__ __launch_bounds__(256)
void finalize(const float* __restrict__ pooled, const float* __restrict__ pstats,
              const float* __restrict__ gstats, float* __restrict__ out)
{
    const int j = blockIdx.x * 256 + threadIdx.x;   // float4 index, 262144 total
    const int e = j << 2;
    const int mt = (e >> 4) & 15;
    const int c  = e >> 8;
    const int b  = c >> 9;
    const int hd = (c >> 6) & 7;
    const int sidx = (b << 7) + (hd << 4) + mt;
    const float s = __expf(pstats[sidx * 2] - gstats[b * 2]) / gstats[b * 2 + 1];
    float4 v = *(const float4*)&pooled[e];
    v.x *= s; v.y *= s; v.z *= s; v.w *= s;
    *(float4*)&out[e] = v;
}

extern "C" void kernel_launch(void* const* d_in, const int* in_sizes, int n_in,
                              void* d_out, int out_size, void* d_ws, size_t ws_size,
                              hipStream_t stream)
{
    const float* x    = (const float*)d_in[0];
    const float* wq_w = (const float*)d_in[1];
    const float* wq_b = (const float*)d_in[2];
    const float* wk_w = (const float*)d_in[3];
    const float* wk_b = (const float*)d_in[4];
    const float* wv_w = (const float*)d_in[5];
    const float* wv_b = (const float*)d_in[6];
    const float* r_h  = (const float*)d_in[7];
    const float* r_w  = (const float*)d_in[8];
    float* out = (float*)d_out;

    const size_t PRN = (size_t)BB * HEAD * NN * DH;
    const size_t WSZ = (size_t)3 * DIMC * DIMC;
    unsigned short* Qh  = (unsigned short*)d_ws;
    unsigned short* Ql  = Qh + PRN;
    unsigned short* Kh  = Ql + PRN;
    unsigned short* Kl  = Kh + PRN;
    unsigned short* Vh  = Kl + PRN;
    unsigned short* Vl  = Vh + PRN;
    unsigned short* XTh = Vl + PRN;
    unsigned short* XTl = XTh + PRN;
    unsigned short* Wh  = XTl + PRN;
    unsigned short* Wl  = Wh + WSZ;
    float* pstats = (float*)(Wl + WSZ);
    float* gstats = pstats + BB * 128 * 2;
    // pooled (4 MB fp32) overlays XT region — XT is dead after qkv_gemm.
    float* pooled = (float*)XTh;

    prep_x<<<dim3(16, 8, 8), 256, 0, stream>>>(x, XTh, XTl);
    prep_w<<<dim3(64, 3), 256, 0, stream>>>(wq_w, wk_w, wv_w, Wh, Wl);
    qkv_gemm<<<dim3(64, 8, 3), 256, 0, stream>>>(XTh, XTl, Wh, Wl,
                                                 wq_b, wk_b, wv_b, r_h, r_w,
                                                 Qh, Ql, Kh, Kl, Vh, Vl);
    flash_pv<<<dim3(16, 8, 8), 256, 0, stream>>>(Qh, Ql, Kh, Kl, Vh, Vl,
                                                 pooled, pstats);
    combine_kernel<<<dim3(8), 128, 0, stream>>>(pstats, gstats);
    finalize<<<dim3(1024), 256, 0, stream>>>(pooled, pstats, gstats, out);
}